// Round 3
// baseline (329.838 us; speedup 1.0000x reference)
//
#include <hip/hip_runtime.h>

// Problem constants (B=8, T=4096, D=1024, C=64, P=512)
// Outputs FLOAT32, concatenated: pattern_emb, assignments, logits, hard_indices, Q
#define O_PE 0
#define O_AS 33554432
#define O_LG 50331648
#define O_HI 67108864
#define O_Q  67141632

// ---------------------------------------------------------------------------
// K0: precompute  (grid = 512 blocks, one per pattern)
//  - inv temperature
//  - K_norm transposed:  knT[c][p]  (fp32, [64][512])
//  - PE table: LN(patterns @ w2 + b2) as fp32 [512][1024]
// ---------------------------------------------------------------------------
__global__ void k0_pre(const float* __restrict__ patterns, const float* __restrict__ w2,
                       const float* __restrict__ b2, const float* __restrict__ ln2g,
                       const float* __restrict__ ln2b, const int* __restrict__ epoch,
                       const int* __restrict__ total_epochs,
                       float* __restrict__ invt, float* __restrict__ knT,
                       float* __restrict__ peb) {
  const int b = blockIdx.x, t = threadIdx.x;
  __shared__ float pat[64];
  __shared__ float red[8];

  if (b == 0 && t == 0) {
    float ep = (float)epoch[0], te = (float)total_epochs[0];
    float warm = te * 0.1f;
    float temp;
    if (ep < warm) temp = 2.0f;
    else {
      float prog = (ep - warm) / (te - warm);
      temp = fmaxf(0.7f, 2.0f - 1.3f * prog);
    }
    invt[0] = 1.0f / temp;
  }

  if (t < 64) pat[t] = patterns[b * 64 + t];
  __syncthreads();

  if (t < 64) {
    float v = pat[t];
    float s = v * v;
    #pragma unroll
    for (int m = 1; m < 64; m <<= 1) s += __shfl_xor(s, m);
    float scale = 1.0f / fmaxf(sqrtf(s), 1e-12f);
    knT[(size_t)t * 512 + b] = v * scale;
  }

  const int d0 = t * 4;
  float4 acc = *(const float4*)&b2[d0];
  #pragma unroll 8
  for (int k = 0; k < 64; ++k) {
    float pk = pat[k];
    float4 w = *(const float4*)&w2[(size_t)k * 1024 + d0];
    acc.x = fmaf(pk, w.x, acc.x);
    acc.y = fmaf(pk, w.y, acc.y);
    acc.z = fmaf(pk, w.z, acc.z);
    acc.w = fmaf(pk, w.w, acc.w);
  }
  float s1 = acc.x + acc.y + acc.z + acc.w;
  float s2 = acc.x*acc.x + acc.y*acc.y + acc.z*acc.z + acc.w*acc.w;
  #pragma unroll
  for (int m = 1; m < 64; m <<= 1) { s1 += __shfl_xor(s1, m); s2 += __shfl_xor(s2, m); }
  const int wid = t >> 6;
  if ((t & 63) == 0) { red[wid] = s1; red[wid + 4] = s2; }
  __syncthreads();
  s1 = red[0] + red[1] + red[2] + red[3];
  s2 = red[4] + red[5] + red[6] + red[7];
  float mu = s1 * (1.0f / 1024.0f);
  float var = s2 * (1.0f / 1024.0f) - mu * mu;
  float rstd = rsqrtf(var + 1e-5f);
  float4 g  = *(const float4*)&ln2g[d0];
  float4 bb = *(const float4*)&ln2b[d0];
  float4 o;
  o.x = (acc.x - mu) * rstd * g.x + bb.x;
  o.y = (acc.y - mu) * rstd * g.y + bb.y;
  o.z = (acc.z - mu) * rstd * g.z + bb.z;
  o.w = (acc.w - mu) * rstd * g.w + bb.w;
  *(float4*)&peb[(size_t)b * 1024 + d0] = o;
}

// ---------------------------------------------------------------------------
// K1: fully fused. 512 blocks x 512 threads (8 waves). 64 rows per block.
// lane = row (all waves). Wave w owns output cols [8w,8w+8) in phase 1 and
// patterns [64w,64w+64) in phase 2. B-operands (w1 / knT) are wave-uniform ->
// SGPR s_loads; only x/Qn go through LDS (1 ds_read_b128 per 4 k / 1 b32 per c).
// ---------------------------------------------------------------------------
__global__ __launch_bounds__(512, 4) void k1_main(
    const float* __restrict__ x, const float* __restrict__ w1,
    const float* __restrict__ b1, const float* __restrict__ ln1g,
    const float* __restrict__ ln1b, const float* __restrict__ knT,
    const float* __restrict__ invtp, const float* __restrict__ peb,
    float* __restrict__ outPe, float* __restrict__ outAs,
    float* __restrict__ outLg, float* __restrict__ outHi,
    float* __restrict__ outQ) {
  __shared__ float4 xs4[16][64];            // x tile: [kc][row ^ kc], 16 KB
  __shared__ float  qnL[64 * 64];           // Qn transposed [c][row], 16 KB
  __shared__ float  red1[8][64], red2[8][64], red3[8][64];
  __shared__ float  avm[8][64];
  __shared__ int    avi[8][64];
  __shared__ int    sidx[64];

  const int tid = threadIdx.x;
  const int l   = tid & 63;                     // lane = row within block
  const int w   = tid >> 6;                     // wave id
  const int wu  = __builtin_amdgcn_readfirstlane(w);  // provably uniform
  const int rowbase = blockIdx.x * 64;
  const size_t row_l = (size_t)(rowbase + l);

  // ---------------- phase 1: h = x @ w1 (cols 8wu..8wu+8 per wave) ----------
  float acc[8];
  #pragma unroll
  for (int j = 0; j < 8; ++j) acc[j] = 0.f;

  const int srow = tid >> 4;                    // [0,32) stage row (low half)
  const int skc  = tid & 15;                    // stage k-chunk
  const float* xrow0 = x + (size_t)(rowbase + srow) * 1024 + skc * 4;
  const float* xrow1 = xrow0 + (size_t)32 * 1024;

  for (int kt = 0; kt < 16; ++kt) {
    const int dbase = kt * 64;
    float4 v0 = *(const float4*)(xrow0 + dbase);
    float4 v1 = *(const float4*)(xrow1 + dbase);
    __syncthreads();
    xs4[skc][srow ^ skc] = v0;                  // XOR-swizzle: conflict-free T-write
    xs4[skc][(srow + 32) ^ skc] = v1;
    __syncthreads();
    #pragma unroll 4
    for (int kc = 0; kc < 16; ++kc) {
      float4 xv = xs4[kc][l ^ kc];              // row l's k-chunk (swizzled slot)
      const float* wp = w1 + (size_t)(dbase + kc * 4) * 64 + wu * 8;  // uniform
      float wv0[8], wv1[8], wv2[8], wv3[8];
      #pragma unroll
      for (int j = 0; j < 8; ++j) {
        wv0[j] = wp[j]; wv1[j] = wp[64 + j]; wv2[j] = wp[128 + j]; wv3[j] = wp[192 + j];
      }
      #pragma unroll
      for (int j = 0; j < 8; ++j)
        acc[j] = fmaf(xv.x, wv0[j],
                 fmaf(xv.y, wv1[j],
                 fmaf(xv.z, wv2[j],
                 fmaf(xv.w, wv3[j], acc[j]))));
    }
  }

  // ---------------- LN + l2norm epilogue (cross-wave reductions) ------------
  float bb[8], gg[8], ee[8];
  {
    const float* bp = b1   + wu * 8;
    const float* gp = ln1g + wu * 8;
    const float* ep = ln1b + wu * 8;
    #pragma unroll
    for (int j = 0; j < 8; ++j) { bb[j] = bp[j]; gg[j] = gp[j]; ee[j] = ep[j]; }
  }
  float h[8]; float ps1 = 0.f, ps2 = 0.f;
  #pragma unroll
  for (int j = 0; j < 8; ++j) { h[j] = acc[j] + bb[j]; ps1 += h[j]; ps2 += h[j]*h[j]; }
  red1[w][l] = ps1; red2[w][l] = ps2;
  __syncthreads();
  float s1 = 0.f, s2 = 0.f;
  #pragma unroll
  for (int v = 0; v < 8; ++v) { s1 += red1[v][l]; s2 += red2[v][l]; }
  const float mu   = s1 * 0.015625f;
  const float var  = s2 * 0.015625f - mu * mu;
  const float rstd = rsqrtf(var + 1e-5f);
  float q[8]; float ps = 0.f;
  #pragma unroll
  for (int j = 0; j < 8; ++j) { q[j] = (h[j] - mu) * rstd * gg[j] + ee[j]; ps += q[j]*q[j]; }
  red3[w][l] = ps;
  // Q output while the reduction settles
  {
    float4 qa; qa.x = q[0]; qa.y = q[1]; qa.z = q[2]; qa.w = q[3];
    float4 qc; qc.x = q[4]; qc.y = q[5]; qc.z = q[6]; qc.w = q[7];
    *(float4*)&outQ[row_l * 64 + wu * 8]     = qa;
    *(float4*)&outQ[row_l * 64 + wu * 8 + 4] = qc;
  }
  __syncthreads();
  float t2 = 0.f;
  #pragma unroll
  for (int v = 0; v < 8; ++v) t2 += red3[v][l];
  const float scl = 1.0f / fmaxf(sqrtf(t2), 1e-12f);
  #pragma unroll
  for (int j = 0; j < 8; ++j) qnL[(wu * 8 + j) * 64 + l] = q[j] * scl;
  __syncthreads();

  // ---------------- phase 2: logits (64 patterns per wave) + argmax ---------
  const float invt = invtp[0];
  float bmax = -3.0e38f; int bidx = 0;
  #pragma unroll
  for (int pp = 0; pp < 2; ++pp) {
    const int pbase = wu * 64 + pp * 32;
    float a2[32];
    #pragma unroll
    for (int j = 0; j < 32; ++j) a2[j] = 0.f;
    #pragma unroll 2
    for (int c = 0; c < 64; ++c) {
      const float qv = qnL[c * 64 + l];
      const float* kp = knT + (size_t)c * 512 + pbase;   // uniform -> s_load
      float kv[32];
      #pragma unroll
      for (int j = 0; j < 32; ++j) kv[j] = kp[j];
      #pragma unroll
      for (int j = 0; j < 32; ++j) a2[j] = fmaf(qv, kv[j], a2[j]);
    }
    #pragma unroll
    for (int j = 0; j < 32; ++j)
      if (a2[j] > bmax) { bmax = a2[j]; bidx = pbase + j; }   // first-max kept
    #pragma unroll
    for (int j4 = 0; j4 < 8; ++j4) {
      float4 o;
      o.x = a2[j4*4 + 0] * invt; o.y = a2[j4*4 + 1] * invt;
      o.z = a2[j4*4 + 2] * invt; o.w = a2[j4*4 + 3] * invt;
      *(float4*)&outLg[row_l * 512 + pbase + j4 * 4] = o;
    }
  }

  // cross-wave argmax (ascending wave = ascending pattern range, strict >)
  avm[w][l] = bmax; avi[w][l] = bidx;
  __syncthreads();
  float bm = avm[0][l]; int bi = avi[0][l];
  #pragma unroll
  for (int v = 1; v < 8; ++v) {
    float m = avm[v][l];
    int   i = avi[v][l];
    if (m > bm) { bm = m; bi = i; }
  }
  if (w == 0) { sidx[l] = bi; outHi[rowbase + l] = (float)bi; }
  __syncthreads();

  // ---------------- assignments: one-hot fp32 rows ----------------
  #pragma unroll
  for (int p = 0; p < 16; ++p) {
    const int e  = tid + p * 512;        // 8192 float4 chunks (64 rows x 128)
    const int r  = e >> 7;
    const int c4 = (e & 127) * 4;
    const int bi2 = sidx[r];
    float4 z; z.x = 0.f; z.y = 0.f; z.z = 0.f; z.w = 0.f;
    if (bi2 >= c4 && bi2 < c4 + 4) ((float*)&z)[bi2 - c4] = 1.0f;
    *(float4*)&outAs[(size_t)(rowbase + r) * 512 + c4] = z;
  }

  // ---------------- pattern_emb gather (PE table is L2-hot) ----------------
  const float4* peb4 = (const float4*)peb;
  float4* outPe4 = (float4*)outPe;
  #pragma unroll
  for (int p = 0; p < 32; ++p) {
    const int e  = tid + p * 512;        // 16384 f4 chunks (64 rows x 256)
    const int r  = e >> 8;
    const int c4 = e & 255;
    outPe4[(size_t)(rowbase + r) * 256 + c4] = peb4[(size_t)sidx[r] * 256 + c4];
  }
}

// ---------------------------------------------------------------------------
extern "C" void kernel_launch(void* const* d_in, const int* in_sizes, int n_in,
                              void* d_out, int out_size, void* d_ws, size_t ws_size,
                              hipStream_t stream) {
  (void)in_sizes; (void)n_in; (void)out_size; (void)ws_size;
  const float* x        = (const float*)d_in[0];
  const float* w1       = (const float*)d_in[1];
  const float* b1       = (const float*)d_in[2];
  const float* ln1g     = (const float*)d_in[3];
  const float* ln1b     = (const float*)d_in[4];
  const float* patterns = (const float*)d_in[5];
  const float* w2       = (const float*)d_in[6];
  const float* b2       = (const float*)d_in[7];
  const float* ln2g     = (const float*)d_in[8];
  const float* ln2b     = (const float*)d_in[9];
  const int*   epoch    = (const int*)d_in[10];
  const int*   total    = (const int*)d_in[11];

  float* out = (float*)d_out;
  float* outPe = out + O_PE;
  float* outAs = out + O_AS;
  float* outLg = out + O_LG;
  float* outHi = out + O_HI;
  float* outQ  = out + O_Q;

  // workspace (bytes): [0..256) invt | [256..131328) knT [64][512]
  //                    [131328..2228480) PE fp32 [512][1024]
  float* wsf  = (float*)d_ws;
  float* invt = wsf;
  float* knT  = wsf + 64;
  float* peb  = (float*)((char*)d_ws + 131328);

  hipLaunchKernelGGL(k0_pre, dim3(512), dim3(256), 0, stream,
                     patterns, w2, b2, ln2g, ln2b, epoch, total, invt, knT, peb);
  hipLaunchKernelGGL(k1_main, dim3(512), dim3(512), 0, stream,
                     x, w1, b1, ln1g, ln1b, knT, invt, peb,
                     outPe, outAs, outLg, outHi, outQ);
}

// Round 4
// 271.159 us; speedup vs baseline: 1.2164x; 1.2164x over previous
//
#include <hip/hip_runtime.h>

// Problem constants (B=8, T=4096, D=1024, C=64, P=512)
// Outputs FLOAT32, concatenated: pattern_emb, assignments, logits, hard_indices, Q
#define O_PE 0
#define O_AS 33554432
#define O_LG 50331648
#define O_HI 67108864
#define O_Q  67141632

// ---------------------------------------------------------------------------
// K0: precompute  (grid = 512 blocks, one per pattern)
//  - inv temperature
//  - K_norm transposed:  knT[c][p]  (fp32, [64][512])
//  - PE table: LN(patterns @ w2 + b2) as fp32 [512][1024]
// ---------------------------------------------------------------------------
__global__ void k0_pre(const float* __restrict__ patterns, const float* __restrict__ w2,
                       const float* __restrict__ b2, const float* __restrict__ ln2g,
                       const float* __restrict__ ln2b, const int* __restrict__ epoch,
                       const int* __restrict__ total_epochs,
                       float* __restrict__ invt, float* __restrict__ knT,
                       float* __restrict__ peb) {
  const int b = blockIdx.x, t = threadIdx.x;
  __shared__ float pat[64];
  __shared__ float red[8];

  if (b == 0 && t == 0) {
    float ep = (float)epoch[0], te = (float)total_epochs[0];
    float warm = te * 0.1f;
    float temp;
    if (ep < warm) temp = 2.0f;
    else {
      float prog = (ep - warm) / (te - warm);
      temp = fmaxf(0.7f, 2.0f - 1.3f * prog);
    }
    invt[0] = 1.0f / temp;
  }

  if (t < 64) pat[t] = patterns[b * 64 + t];
  __syncthreads();

  if (t < 64) {
    float v = pat[t];
    float s = v * v;
    #pragma unroll
    for (int m = 1; m < 64; m <<= 1) s += __shfl_xor(s, m);
    float scale = 1.0f / fmaxf(sqrtf(s), 1e-12f);
    knT[(size_t)t * 512 + b] = v * scale;
  }

  const int d0 = t * 4;
  float4 acc = *(const float4*)&b2[d0];
  #pragma unroll 8
  for (int k = 0; k < 64; ++k) {
    float pk = pat[k];
    float4 w = *(const float4*)&w2[(size_t)k * 1024 + d0];
    acc.x = fmaf(pk, w.x, acc.x);
    acc.y = fmaf(pk, w.y, acc.y);
    acc.z = fmaf(pk, w.z, acc.z);
    acc.w = fmaf(pk, w.w, acc.w);
  }
  float s1 = acc.x + acc.y + acc.z + acc.w;
  float s2 = acc.x*acc.x + acc.y*acc.y + acc.z*acc.z + acc.w*acc.w;
  #pragma unroll
  for (int m = 1; m < 64; m <<= 1) { s1 += __shfl_xor(s1, m); s2 += __shfl_xor(s2, m); }
  const int wid = t >> 6;
  if ((t & 63) == 0) { red[wid] = s1; red[wid + 4] = s2; }
  __syncthreads();
  s1 = red[0] + red[1] + red[2] + red[3];
  s2 = red[4] + red[5] + red[6] + red[7];
  float mu = s1 * (1.0f / 1024.0f);
  float var = s2 * (1.0f / 1024.0f) - mu * mu;
  float rstd = rsqrtf(var + 1e-5f);
  float4 g  = *(const float4*)&ln2g[d0];
  float4 bb = *(const float4*)&ln2b[d0];
  float4 o;
  o.x = (acc.x - mu) * rstd * g.x + bb.x;
  o.y = (acc.y - mu) * rstd * g.y + bb.y;
  o.z = (acc.z - mu) * rstd * g.z + bb.z;
  o.w = (acc.w - mu) * rstd * g.w + bb.w;
  *(float4*)&peb[(size_t)b * 1024 + d0] = o;
}

// ---------------------------------------------------------------------------
// K1a: GEMM1 (x @ w1) + bias + LayerNorm + l2norm.  Writes Q and Qn (global).
// 256 blocks x 128 threads. 128 rows/block. Thread tile 8 rows x 8 cols.
// Per k-step: 2 ds_read_b128 (rows) + 2 ds_read_b128 (cols) per 64 FMA.
// ---------------------------------------------------------------------------
__global__ __launch_bounds__(128, 3) void k1a(
    const float* __restrict__ x, const float* __restrict__ w1,
    const float* __restrict__ b1, const float* __restrict__ ln1g,
    const float* __restrict__ ln1b,
    float* __restrict__ outQ, float* __restrict__ qng) {
  __shared__ float xsT[32][132];   // [k][row], stride 132 (=4 mod 32 banks)
  __shared__ float w1s[32][68];    // [k][col]

  const int tid = threadIdx.x;
  const int ct = tid & 7;          // 8 col-threads * 8 cols = 64
  const int rt = tid >> 3;         // 16 row-threads * 8 rows = 128
  const int c0 = ct * 8;
  const int r0 = rt * 8;
  const int rowbase = blockIdx.x * 128;

  float acc[8][8];
  #pragma unroll
  for (int i = 0; i < 8; ++i)
    #pragma unroll
    for (int j = 0; j < 8; ++j) acc[i][j] = 0.f;

  for (int kt = 0; kt < 32; ++kt) {
    const int kb = kt * 32;
    // global loads (held in regs across the sync)
    float4 xv[8];
    #pragma unroll
    for (int p = 0; p < 8; ++p) {
      const int id = tid + p * 128;
      const int row = id >> 3, kc = id & 7;
      xv[p] = *(const float4*)&x[(size_t)(rowbase + row) * 1024 + kb + kc * 4];
    }
    float4 wv[4];
    #pragma unroll
    for (int p = 0; p < 4; ++p) {
      const int id = tid + p * 128;
      const int kr = id >> 4, c4 = (id & 15) * 4;
      wv[p] = *(const float4*)&w1[(size_t)(kb + kr) * 64 + c4];
    }
    __syncthreads();   // previous tile fully consumed
    #pragma unroll
    for (int p = 0; p < 8; ++p) {
      const int id = tid + p * 128;
      const int row = id >> 3, kc = id & 7;
      xsT[kc * 4 + 0][row] = xv[p].x;
      xsT[kc * 4 + 1][row] = xv[p].y;
      xsT[kc * 4 + 2][row] = xv[p].z;
      xsT[kc * 4 + 3][row] = xv[p].w;
    }
    #pragma unroll
    for (int p = 0; p < 4; ++p) {
      const int id = tid + p * 128;
      const int kr = id >> 4, c4 = (id & 15) * 4;
      *(float4*)&w1s[kr][c4] = wv[p];
    }
    __syncthreads();
    #pragma unroll 4
    for (int kk = 0; kk < 32; ++kk) {
      float4 a0 = *(float4*)&xsT[kk][r0];
      float4 a1 = *(float4*)&xsT[kk][r0 + 4];
      float4 b0 = *(float4*)&w1s[kk][c0];
      float4 b1v = *(float4*)&w1s[kk][c0 + 4];
      float av[8] = {a0.x, a0.y, a0.z, a0.w, a1.x, a1.y, a1.z, a1.w};
      float bv[8] = {b0.x, b0.y, b0.z, b0.w, b1v.x, b1v.y, b1v.z, b1v.w};
      #pragma unroll
      for (int i = 0; i < 8; ++i)
        #pragma unroll
        for (int j = 0; j < 8; ++j)
          acc[i][j] = fmaf(av[i], bv[j], acc[i][j]);
    }
  }

  // epilogue: +b1, LayerNorm over 64 cols (8 regs x 8 ct-lanes), l2norm
  float bb[8], gg[8], ee[8];
  {
    float4 t0 = *(const float4*)&b1[c0];
    float4 t1 = *(const float4*)&b1[c0 + 4];
    float4 t2 = *(const float4*)&ln1g[c0];
    float4 t3 = *(const float4*)&ln1g[c0 + 4];
    float4 t4 = *(const float4*)&ln1b[c0];
    float4 t5 = *(const float4*)&ln1b[c0 + 4];
    bb[0]=t0.x; bb[1]=t0.y; bb[2]=t0.z; bb[3]=t0.w; bb[4]=t1.x; bb[5]=t1.y; bb[6]=t1.z; bb[7]=t1.w;
    gg[0]=t2.x; gg[1]=t2.y; gg[2]=t2.z; gg[3]=t2.w; gg[4]=t3.x; gg[5]=t3.y; gg[6]=t3.z; gg[7]=t3.w;
    ee[0]=t4.x; ee[1]=t4.y; ee[2]=t4.z; ee[3]=t4.w; ee[4]=t5.x; ee[5]=t5.y; ee[6]=t5.z; ee[7]=t5.w;
  }
  #pragma unroll
  for (int i = 0; i < 8; ++i) {
    const size_t row = (size_t)(rowbase + r0 + i);
    float h[8]; float s1 = 0.f, s2 = 0.f;
    #pragma unroll
    for (int j = 0; j < 8; ++j) { h[j] = acc[i][j] + bb[j]; s1 += h[j]; s2 += h[j]*h[j]; }
    #pragma unroll
    for (int m = 1; m < 8; m <<= 1) { s1 += __shfl_xor(s1, m); s2 += __shfl_xor(s2, m); }
    const float mu   = s1 * 0.015625f;
    const float var  = s2 * 0.015625f - mu * mu;
    const float rstd = rsqrtf(var + 1e-5f);
    float q[8]; float t2 = 0.f;
    #pragma unroll
    for (int j = 0; j < 8; ++j) { q[j] = (h[j] - mu) * rstd * gg[j] + ee[j]; t2 += q[j]*q[j]; }
    #pragma unroll
    for (int m = 1; m < 8; m <<= 1) t2 += __shfl_xor(t2, m);
    const float scl = 1.0f / fmaxf(sqrtf(t2), 1e-12f);
    float4 qa, qc;
    qa.x = q[0]; qa.y = q[1]; qa.z = q[2]; qa.w = q[3];
    qc.x = q[4]; qc.y = q[5]; qc.z = q[6]; qc.w = q[7];
    *(float4*)&outQ[row * 64 + c0]     = qa;
    *(float4*)&outQ[row * 64 + c0 + 4] = qc;
    float4 na, nc;
    na.x = q[0]*scl; na.y = q[1]*scl; na.z = q[2]*scl; na.w = q[3]*scl;
    nc.x = q[4]*scl; nc.y = q[5]*scl; nc.z = q[6]*scl; nc.w = q[7]*scl;
    *(float4*)&qng[row * 64 + c0]     = na;
    *(float4*)&qng[row * 64 + c0 + 4] = nc;
  }
}

// ---------------------------------------------------------------------------
// K1b: logits = Qn @ KnT, argmax, one-hot assignments, PE gather, hard idx.
// 512 blocks x 256 threads. 64 rows/block. Thread tile 4 rows x 8 patterns,
// rows strided 16 (rt, rt+16, rt+32, rt+48) for bank-spread b32 reads.
// ---------------------------------------------------------------------------
__global__ __launch_bounds__(256, 3) void k1b(
    const float* __restrict__ qng, const float* __restrict__ knT,
    const float* __restrict__ invtp, const float* __restrict__ peb,
    float* __restrict__ outPe, float* __restrict__ outAs,
    float* __restrict__ outLg, float* __restrict__ outHi) {
  __shared__ float qns[64][65];    // [row][c], pad 65 -> bank = row + c
  __shared__ float kns[64][128];   // [c][p-chunk]
  __shared__ int   sidx[64];

  const int tid = threadIdx.x;
  const int pt = tid & 15;         // 16 p-threads * 8 = 128 p per chunk
  const int rt = tid >> 4;         // 16 row-threads, rows rt + 16*i
  const int rowbase = blockIdx.x * 64;

  // stage Qn rows (row-major, conflict-spread via pad-65)
  #pragma unroll
  for (int p = 0; p < 4; ++p) {
    const int id = tid + p * 256;
    const int row = id >> 4, cc = (id & 15) * 4;
    float4 v = *(const float4*)&qng[(size_t)(rowbase + row) * 64 + cc];
    qns[row][cc + 0] = v.x; qns[row][cc + 1] = v.y;
    qns[row][cc + 2] = v.z; qns[row][cc + 3] = v.w;
  }

  const float invt = invtp[0];
  float bm[4]; int bi[4];
  #pragma unroll
  for (int i = 0; i < 4; ++i) { bm[i] = -3.0e38f; bi[i] = 0; }

  for (int ch = 0; ch < 4; ++ch) {
    __syncthreads();   // covers qns staging (ch=0) and kns reuse (ch>0)
    #pragma unroll
    for (int p = 0; p < 8; ++p) {
      const int id = tid + p * 256;
      const int cr = id >> 5, pc = (id & 31) * 4;
      *(float4*)&kns[cr][pc] = *(const float4*)&knT[(size_t)cr * 512 + ch * 128 + pc];
    }
    __syncthreads();

    float a2[4][8];
    #pragma unroll
    for (int i = 0; i < 4; ++i)
      #pragma unroll
      for (int j = 0; j < 8; ++j) a2[i][j] = 0.f;

    #pragma unroll 2
    for (int c = 0; c < 64; ++c) {
      float4 k0 = *(float4*)&kns[c][pt * 8];
      float4 k1 = *(float4*)&kns[c][pt * 8 + 4];
      float kv[8] = {k0.x, k0.y, k0.z, k0.w, k1.x, k1.y, k1.z, k1.w};
      float qv[4];
      qv[0] = qns[rt][c]; qv[1] = qns[rt + 16][c];
      qv[2] = qns[rt + 32][c]; qv[3] = qns[rt + 48][c];
      #pragma unroll
      for (int i = 0; i < 4; ++i)
        #pragma unroll
        for (int j = 0; j < 8; ++j)
          a2[i][j] = fmaf(qv[i], kv[j], a2[i][j]);
    }

    #pragma unroll
    for (int i = 0; i < 4; ++i) {
      const size_t row = (size_t)(rowbase + rt + 16 * i);
      float v[8];
      #pragma unroll
      for (int j = 0; j < 8; ++j) v[j] = a2[i][j] * invt;
      const int pb = ch * 128 + pt * 8;
      #pragma unroll
      for (int j = 0; j < 8; ++j)
        if (v[j] > bm[i]) { bm[i] = v[j]; bi[i] = pb + j; }   // ascending p, first max
      float4 o0, o1;
      o0.x = v[0]; o0.y = v[1]; o0.z = v[2]; o0.w = v[3];
      o1.x = v[4]; o1.y = v[5]; o1.z = v[6]; o1.w = v[7];
      *(float4*)&outLg[row * 512 + pb]     = o0;
      *(float4*)&outLg[row * 512 + pb + 4] = o1;
    }
  }

  // cross-thread argmax over pt (tie -> min index)
  #pragma unroll
  for (int i = 0; i < 4; ++i) {
    #pragma unroll
    for (int m = 1; m < 16; m <<= 1) {
      float ov = __shfl_xor(bm[i], m);
      int   oi = __shfl_xor(bi[i], m);
      if (ov > bm[i] || (ov == bm[i] && oi < bi[i])) { bm[i] = ov; bi[i] = oi; }
    }
    if (pt == 0) {
      sidx[rt + 16 * i] = bi[i];
      outHi[rowbase + rt + 16 * i] = (float)bi[i];
    }
  }
  __syncthreads();

  // one-hot assignments (64 rows x 512)
  #pragma unroll
  for (int p = 0; p < 32; ++p) {
    const int id = tid + p * 256;
    const int r = id >> 7, c4 = (id & 127) * 4;
    const int b = sidx[r];
    float4 z; z.x = 0.f; z.y = 0.f; z.z = 0.f; z.w = 0.f;
    if (b >= c4 && b < c4 + 4) ((float*)&z)[b - c4] = 1.0f;
    *(float4*)&outAs[(size_t)(rowbase + r) * 512 + c4] = z;
  }

  // pattern_emb gather (PE table is L2-hot, 2 MB)
  const float4* peb4 = (const float4*)peb;
  float4* o4 = (float4*)outPe;
  #pragma unroll 4
  for (int p = 0; p < 64; ++p) {
    const int id = tid + p * 256;
    const int r = id >> 8, c4 = id & 255;
    o4[(size_t)(rowbase + r) * 256 + c4] = peb4[(size_t)sidx[r] * 256 + c4];
  }
}

// ---------------------------------------------------------------------------
extern "C" void kernel_launch(void* const* d_in, const int* in_sizes, int n_in,
                              void* d_out, int out_size, void* d_ws, size_t ws_size,
                              hipStream_t stream) {
  (void)in_sizes; (void)n_in; (void)out_size; (void)ws_size;
  const float* x        = (const float*)d_in[0];
  const float* w1       = (const float*)d_in[1];
  const float* b1       = (const float*)d_in[2];
  const float* ln1g     = (const float*)d_in[3];
  const float* ln1b     = (const float*)d_in[4];
  const float* patterns = (const float*)d_in[5];
  const float* w2       = (const float*)d_in[6];
  const float* b2       = (const float*)d_in[7];
  const float* ln2g     = (const float*)d_in[8];
  const float* ln2b     = (const float*)d_in[9];
  const int*   epoch    = (const int*)d_in[10];
  const int*   total    = (const int*)d_in[11];

  float* out = (float*)d_out;
  float* outPe = out + O_PE;
  float* outAs = out + O_AS;
  float* outLg = out + O_LG;
  float* outHi = out + O_HI;
  float* outQ  = out + O_Q;

  // workspace (bytes): [0..256) invt | [256..131328) knT [64][512]
  //                    [131328..2228480) PE fp32 [512][1024]
  //                    [2228480..10617088) Qn fp32 [32768][64]
  float* wsf  = (float*)d_ws;
  float* invt = wsf;
  float* knT  = wsf + 64;
  float* peb  = (float*)((char*)d_ws + 131328);
  float* qng  = (float*)((char*)d_ws + 2228480);

  hipLaunchKernelGGL(k0_pre, dim3(512), dim3(256), 0, stream,
                     patterns, w2, b2, ln2g, ln2b, epoch, total, invt, knT, peb);
  hipLaunchKernelGGL(k1a, dim3(256), dim3(128), 0, stream,
                     x, w1, b1, ln1g, ln1b, outQ, qng);
  hipLaunchKernelGGL(k1b, dim3(512), dim3(256), 0, stream,
                     qng, knT, invt, peb, outPe, outAs, outLg, outHi);
}

// Round 5
// 185.697 us; speedup vs baseline: 1.7762x; 1.4602x over previous
//
#include <hip/hip_runtime.h>

// Problem constants (B=8, T=4096, D=1024, C=64, P=512)
// Outputs FLOAT32, concatenated: pattern_emb, assignments, logits, hard_indices, Q
#define O_PE 0
#define O_AS 33554432
#define O_LG 50331648
#define O_HI 67108864
#define O_Q  67141632

// ---------------------------------------------------------------------------
// K0: precompute  (grid = 512 blocks, one per pattern)
//  - inv temperature
//  - K_norm transposed:  knT[c][p]  (fp32, [64][512])
//  - PE table: LN(patterns @ w2 + b2) as fp32 [512][1024]
// ---------------------------------------------------------------------------
__global__ void k0_pre(const float* __restrict__ patterns, const float* __restrict__ w2,
                       const float* __restrict__ b2, const float* __restrict__ ln2g,
                       const float* __restrict__ ln2b, const int* __restrict__ epoch,
                       const int* __restrict__ total_epochs,
                       float* __restrict__ invt, float* __restrict__ knT,
                       float* __restrict__ peb) {
  const int b = blockIdx.x, t = threadIdx.x;
  __shared__ float pat[64];
  __shared__ float red[8];

  if (b == 0 && t == 0) {
    float ep = (float)epoch[0], te = (float)total_epochs[0];
    float warm = te * 0.1f;
    float temp;
    if (ep < warm) temp = 2.0f;
    else {
      float prog = (ep - warm) / (te - warm);
      temp = fmaxf(0.7f, 2.0f - 1.3f * prog);
    }
    invt[0] = 1.0f / temp;
  }

  if (t < 64) pat[t] = patterns[b * 64 + t];
  __syncthreads();

  if (t < 64) {
    float v = pat[t];
    float s = v * v;
    #pragma unroll
    for (int m = 1; m < 64; m <<= 1) s += __shfl_xor(s, m);
    float scale = 1.0f / fmaxf(sqrtf(s), 1e-12f);
    knT[(size_t)t * 512 + b] = v * scale;
  }

  const int d0 = t * 4;
  float4 acc = *(const float4*)&b2[d0];
  #pragma unroll 8
  for (int k = 0; k < 64; ++k) {
    float pk = pat[k];
    float4 w = *(const float4*)&w2[(size_t)k * 1024 + d0];
    acc.x = fmaf(pk, w.x, acc.x);
    acc.y = fmaf(pk, w.y, acc.y);
    acc.z = fmaf(pk, w.z, acc.z);
    acc.w = fmaf(pk, w.w, acc.w);
  }
  float s1 = acc.x + acc.y + acc.z + acc.w;
  float s2 = acc.x*acc.x + acc.y*acc.y + acc.z*acc.z + acc.w*acc.w;
  #pragma unroll
  for (int m = 1; m < 64; m <<= 1) { s1 += __shfl_xor(s1, m); s2 += __shfl_xor(s2, m); }
  const int wid = t >> 6;
  if ((t & 63) == 0) { red[wid] = s1; red[wid + 4] = s2; }
  __syncthreads();
  s1 = red[0] + red[1] + red[2] + red[3];
  s2 = red[4] + red[5] + red[6] + red[7];
  float mu = s1 * (1.0f / 1024.0f);
  float var = s2 * (1.0f / 1024.0f) - mu * mu;
  float rstd = rsqrtf(var + 1e-5f);
  float4 g  = *(const float4*)&ln2g[d0];
  float4 bb = *(const float4*)&ln2b[d0];
  float4 o;
  o.x = (acc.x - mu) * rstd * g.x + bb.x;
  o.y = (acc.y - mu) * rstd * g.y + bb.y;
  o.z = (acc.z - mu) * rstd * g.z + bb.z;
  o.w = (acc.w - mu) * rstd * g.w + bb.w;
  *(float4*)&peb[(size_t)b * 1024 + d0] = o;
}

// ---------------------------------------------------------------------------
// K1a: GEMM1 partials.  Grid = 1024 blocks = 256 row-blocks x 4 K-splits.
// Each block: 128 rows x 64 cols over a 256-wide K chunk, 128 thr, 8x8 tile.
// Partials (no bias) -> part[ks][row][col]  (lives in the outAs region).
// ---------------------------------------------------------------------------
__global__ __launch_bounds__(128) void k1a(
    const float* __restrict__ x, const float* __restrict__ w1,
    float* __restrict__ part) {
  __shared__ float xsT[32][132];   // [k][row]
  __shared__ float w1s[32][68];    // [k][col]

  const int tid = threadIdx.x;
  const int ks  = blockIdx.x & 3;       // K-split
  const int rb  = blockIdx.x >> 2;      // row-block
  const int ct = tid & 7;
  const int rt = tid >> 3;
  const int c0 = ct * 8;
  const int r0 = rt * 8;
  const int rowbase = rb * 128;
  const int kbase   = ks * 256;

  float acc[8][8];
  #pragma unroll
  for (int i = 0; i < 8; ++i)
    #pragma unroll
    for (int j = 0; j < 8; ++j) acc[i][j] = 0.f;

  for (int kt = 0; kt < 8; ++kt) {
    const int kb = kbase + kt * 32;
    float4 xv[8];
    #pragma unroll
    for (int p = 0; p < 8; ++p) {
      const int id = tid + p * 128;
      const int row = id >> 3, kc = id & 7;
      xv[p] = *(const float4*)&x[(size_t)(rowbase + row) * 1024 + kb + kc * 4];
    }
    float4 wv[4];
    #pragma unroll
    for (int p = 0; p < 4; ++p) {
      const int id = tid + p * 128;
      const int kr = id >> 4, c4 = (id & 15) * 4;
      wv[p] = *(const float4*)&w1[(size_t)(kb + kr) * 64 + c4];
    }
    __syncthreads();
    #pragma unroll
    for (int p = 0; p < 8; ++p) {
      const int id = tid + p * 128;
      const int row = id >> 3, kc = id & 7;
      xsT[kc * 4 + 0][row] = xv[p].x;
      xsT[kc * 4 + 1][row] = xv[p].y;
      xsT[kc * 4 + 2][row] = xv[p].z;
      xsT[kc * 4 + 3][row] = xv[p].w;
    }
    #pragma unroll
    for (int p = 0; p < 4; ++p) {
      const int id = tid + p * 128;
      const int kr = id >> 4, c4 = (id & 15) * 4;
      *(float4*)&w1s[kr][c4] = wv[p];
    }
    __syncthreads();
    #pragma unroll 4
    for (int kk = 0; kk < 32; ++kk) {
      float4 a0 = *(float4*)&xsT[kk][r0];
      float4 a1 = *(float4*)&xsT[kk][r0 + 4];
      float4 b0 = *(float4*)&w1s[kk][c0];
      float4 b1v = *(float4*)&w1s[kk][c0 + 4];
      float av[8] = {a0.x, a0.y, a0.z, a0.w, a1.x, a1.y, a1.z, a1.w};
      float bv[8] = {b0.x, b0.y, b0.z, b0.w, b1v.x, b1v.y, b1v.z, b1v.w};
      #pragma unroll
      for (int i = 0; i < 8; ++i)
        #pragma unroll
        for (int j = 0; j < 8; ++j)
          acc[i][j] = fmaf(av[i], bv[j], acc[i][j]);
    }
  }

  float* base = part + (size_t)ks * 2097152 + (size_t)(rowbase + r0) * 64 + c0;
  #pragma unroll
  for (int i = 0; i < 8; ++i) {
    float4 p0, p1;
    p0.x = acc[i][0]; p0.y = acc[i][1]; p0.z = acc[i][2]; p0.w = acc[i][3];
    p1.x = acc[i][4]; p1.y = acc[i][5]; p1.z = acc[i][6]; p1.w = acc[i][7];
    *(float4*)(base + (size_t)i * 64)     = p0;
    *(float4*)(base + (size_t)i * 64 + 4) = p1;
  }
}

// ---------------------------------------------------------------------------
// K1r: reduce 4 K-split partials + bias + LayerNorm + l2norm -> Q, Qn.
// Grid = 512 blocks x 256 thr; 64 rows/block; thread = (row, 16-col slice);
// 4 threads per row -> row reduction via 2 shuffles.
// ---------------------------------------------------------------------------
__global__ __launch_bounds__(256) void k1r(
    const float* __restrict__ part, const float* __restrict__ b1,
    const float* __restrict__ ln1g, const float* __restrict__ ln1b,
    float* __restrict__ outQ, float* __restrict__ qng) {
  const int tid = threadIdx.x;
  const size_t row = (size_t)blockIdx.x * 64 + (tid >> 2);
  const int c0 = (tid & 3) * 16;

  float h[16];
  #pragma unroll
  for (int j4 = 0; j4 < 4; ++j4) {
    float4 a = *(const float4*)&part[row * 64 + c0 + j4 * 4];
    h[j4*4+0] = a.x; h[j4*4+1] = a.y; h[j4*4+2] = a.z; h[j4*4+3] = a.w;
  }
  #pragma unroll
  for (int ks = 1; ks < 4; ++ks) {
    #pragma unroll
    for (int j4 = 0; j4 < 4; ++j4) {
      float4 a = *(const float4*)&part[(size_t)ks * 2097152 + row * 64 + c0 + j4 * 4];
      h[j4*4+0] += a.x; h[j4*4+1] += a.y; h[j4*4+2] += a.z; h[j4*4+3] += a.w;
    }
  }
  #pragma unroll
  for (int j4 = 0; j4 < 4; ++j4) {
    float4 b = *(const float4*)&b1[c0 + j4 * 4];
    h[j4*4+0] += b.x; h[j4*4+1] += b.y; h[j4*4+2] += b.z; h[j4*4+3] += b.w;
  }

  float s1 = 0.f, s2 = 0.f;
  #pragma unroll
  for (int j = 0; j < 16; ++j) { s1 += h[j]; s2 += h[j] * h[j]; }
  s1 += __shfl_xor(s1, 1); s2 += __shfl_xor(s2, 1);
  s1 += __shfl_xor(s1, 2); s2 += __shfl_xor(s2, 2);
  const float mu   = s1 * 0.015625f;
  const float var  = s2 * 0.015625f - mu * mu;
  const float rstd = rsqrtf(var + 1e-5f);

  float q[16]; float t2 = 0.f;
  #pragma unroll
  for (int j4 = 0; j4 < 4; ++j4) {
    float4 g = *(const float4*)&ln1g[c0 + j4 * 4];
    float4 e = *(const float4*)&ln1b[c0 + j4 * 4];
    q[j4*4+0] = (h[j4*4+0] - mu) * rstd * g.x + e.x;
    q[j4*4+1] = (h[j4*4+1] - mu) * rstd * g.y + e.y;
    q[j4*4+2] = (h[j4*4+2] - mu) * rstd * g.z + e.z;
    q[j4*4+3] = (h[j4*4+3] - mu) * rstd * g.w + e.w;
  }
  #pragma unroll
  for (int j = 0; j < 16; ++j) t2 += q[j] * q[j];
  t2 += __shfl_xor(t2, 1);
  t2 += __shfl_xor(t2, 2);
  const float scl = 1.0f / fmaxf(sqrtf(t2), 1e-12f);

  #pragma unroll
  for (int j4 = 0; j4 < 4; ++j4) {
    float4 qo, no;
    qo.x = q[j4*4+0]; qo.y = q[j4*4+1]; qo.z = q[j4*4+2]; qo.w = q[j4*4+3];
    no.x = qo.x * scl; no.y = qo.y * scl; no.z = qo.z * scl; no.w = qo.w * scl;
    *(float4*)&outQ[row * 64 + c0 + j4 * 4] = qo;
    *(float4*)&qng[row * 64 + c0 + j4 * 4]  = no;
  }
}

// ---------------------------------------------------------------------------
// K1b: logits = Qn @ KnT, argmax, one-hot assignments, PE gather, hard idx.
// 512 blocks x 256 threads. 64 rows/block. Thread tile 4 rows x 8 patterns.
// ---------------------------------------------------------------------------
__global__ __launch_bounds__(256, 3) void k1b(
    const float* __restrict__ qng, const float* __restrict__ knT,
    const float* __restrict__ invtp, const float* __restrict__ peb,
    float* __restrict__ outPe, float* __restrict__ outAs,
    float* __restrict__ outLg, float* __restrict__ outHi) {
  __shared__ float qns[64][65];    // [row][c], pad 65
  __shared__ float kns[64][128];   // [c][p-chunk]
  __shared__ int   sidx[64];

  const int tid = threadIdx.x;
  const int pt = tid & 15;
  const int rt = tid >> 4;
  const int rowbase = blockIdx.x * 64;

  #pragma unroll
  for (int p = 0; p < 4; ++p) {
    const int id = tid + p * 256;
    const int row = id >> 4, cc = (id & 15) * 4;
    float4 v = *(const float4*)&qng[(size_t)(rowbase + row) * 64 + cc];
    qns[row][cc + 0] = v.x; qns[row][cc + 1] = v.y;
    qns[row][cc + 2] = v.z; qns[row][cc + 3] = v.w;
  }

  const float invt = invtp[0];
  float bm[4]; int bi[4];
  #pragma unroll
  for (int i = 0; i < 4; ++i) { bm[i] = -3.0e38f; bi[i] = 0; }

  for (int ch = 0; ch < 4; ++ch) {
    __syncthreads();
    #pragma unroll
    for (int p = 0; p < 8; ++p) {
      const int id = tid + p * 256;
      const int cr = id >> 5, pc = (id & 31) * 4;
      *(float4*)&kns[cr][pc] = *(const float4*)&knT[(size_t)cr * 512 + ch * 128 + pc];
    }
    __syncthreads();

    float a2[4][8];
    #pragma unroll
    for (int i = 0; i < 4; ++i)
      #pragma unroll
      for (int j = 0; j < 8; ++j) a2[i][j] = 0.f;

    #pragma unroll 2
    for (int c = 0; c < 64; ++c) {
      float4 k0 = *(float4*)&kns[c][pt * 8];
      float4 k1 = *(float4*)&kns[c][pt * 8 + 4];
      float kv[8] = {k0.x, k0.y, k0.z, k0.w, k1.x, k1.y, k1.z, k1.w};
      float qv[4];
      qv[0] = qns[rt][c]; qv[1] = qns[rt + 16][c];
      qv[2] = qns[rt + 32][c]; qv[3] = qns[rt + 48][c];
      #pragma unroll
      for (int i = 0; i < 4; ++i)
        #pragma unroll
        for (int j = 0; j < 8; ++j)
          a2[i][j] = fmaf(qv[i], kv[j], a2[i][j]);
    }

    #pragma unroll
    for (int i = 0; i < 4; ++i) {
      const size_t row = (size_t)(rowbase + rt + 16 * i);
      float v[8];
      #pragma unroll
      for (int j = 0; j < 8; ++j) v[j] = a2[i][j] * invt;
      const int pb = ch * 128 + pt * 8;
      #pragma unroll
      for (int j = 0; j < 8; ++j)
        if (v[j] > bm[i]) { bm[i] = v[j]; bi[i] = pb + j; }
      float4 o0, o1;
      o0.x = v[0]; o0.y = v[1]; o0.z = v[2]; o0.w = v[3];
      o1.x = v[4]; o1.y = v[5]; o1.z = v[6]; o1.w = v[7];
      *(float4*)&outLg[row * 512 + pb]     = o0;
      *(float4*)&outLg[row * 512 + pb + 4] = o1;
    }
  }

  #pragma unroll
  for (int i = 0; i < 4; ++i) {
    #pragma unroll
    for (int m = 1; m < 16; m <<= 1) {
      float ov = __shfl_xor(bm[i], m);
      int   oi = __shfl_xor(bi[i], m);
      if (ov > bm[i] || (ov == bm[i] && oi < bi[i])) { bm[i] = ov; bi[i] = oi; }
    }
    if (pt == 0) {
      sidx[rt + 16 * i] = bi[i];
      outHi[rowbase + rt + 16 * i] = (float)bi[i];
    }
  }
  __syncthreads();

  #pragma unroll
  for (int p = 0; p < 32; ++p) {
    const int id = tid + p * 256;
    const int r = id >> 7, c4 = (id & 127) * 4;
    const int b = sidx[r];
    float4 z; z.x = 0.f; z.y = 0.f; z.z = 0.f; z.w = 0.f;
    if (b >= c4 && b < c4 + 4) ((float*)&z)[b - c4] = 1.0f;
    *(float4*)&outAs[(size_t)(rowbase + r) * 512 + c4] = z;
  }

  const float4* peb4 = (const float4*)peb;
  float4* o4 = (float4*)outPe;
  #pragma unroll 4
  for (int p = 0; p < 64; ++p) {
    const int id = tid + p * 256;
    const int r = id >> 8, c4 = id & 255;
    o4[(size_t)(rowbase + r) * 256 + c4] = peb4[(size_t)sidx[r] * 256 + c4];
  }
}

// ---------------------------------------------------------------------------
extern "C" void kernel_launch(void* const* d_in, const int* in_sizes, int n_in,
                              void* d_out, int out_size, void* d_ws, size_t ws_size,
                              hipStream_t stream) {
  (void)in_sizes; (void)n_in; (void)out_size; (void)ws_size;
  const float* x        = (const float*)d_in[0];
  const float* w1       = (const float*)d_in[1];
  const float* b1       = (const float*)d_in[2];
  const float* ln1g     = (const float*)d_in[3];
  const float* ln1b     = (const float*)d_in[4];
  const float* patterns = (const float*)d_in[5];
  const float* w2       = (const float*)d_in[6];
  const float* b2       = (const float*)d_in[7];
  const float* ln2g     = (const float*)d_in[8];
  const float* ln2b     = (const float*)d_in[9];
  const int*   epoch    = (const int*)d_in[10];
  const int*   total    = (const int*)d_in[11];

  float* out = (float*)d_out;
  float* outPe = out + O_PE;
  float* outAs = out + O_AS;
  float* outLg = out + O_LG;
  float* outHi = out + O_HI;
  float* outQ  = out + O_Q;

  // workspace (bytes): [0..256) invt | [256..131328) knT [64][512]
  //                    [131328..2228480) PE fp32 [512][1024]
  //                    [2228480..10617088) Qn fp32 [32768][64]
  // GEMM1 partials [4][32768][64] fp32 (33.5 MB) live in the outAs region
  // (written by k1a, consumed by k1r, overwritten by k1b's one-hot).
  float* wsf  = (float*)d_ws;
  float* invt = wsf;
  float* knT  = wsf + 64;
  float* peb  = (float*)((char*)d_ws + 131328);
  float* qng  = (float*)((char*)d_ws + 2228480);
  float* part = outAs;

  hipLaunchKernelGGL(k0_pre, dim3(512), dim3(256), 0, stream,
                     patterns, w2, b2, ln2g, ln2b, epoch, total, invt, knT, peb);
  hipLaunchKernelGGL(k1a, dim3(1024), dim3(128), 0, stream,
                     x, w1, part);
  hipLaunchKernelGGL(k1r, dim3(512), dim3(256), 0, stream,
                     part, b1, ln1g, ln1b, outQ, qng);
  hipLaunchKernelGGL(k1b, dim3(512), dim3(256), 0, stream,
                     qng, knT, invt, peb, outPe, outAs, outLg, outHi);
}

// Round 6
// 159.828 us; speedup vs baseline: 2.0637x; 1.1619x over previous
//
#include <hip/hip_runtime.h>

// Problem constants (B=8, T=4096, D=1024, C=64, P=512)
// Outputs FLOAT32, concatenated: pattern_emb, assignments, logits, hard_indices, Q
#define O_PE 0
#define O_AS 33554432
#define O_LG 50331648
#define O_HI 67108864
#define O_Q  67141632

// ---------------------------------------------------------------------------
// K0: precompute  (grid = 512 blocks, one per pattern)
//  - inv temperature
//  - K_norm transposed:  knT[c][p]  (fp32, [64][512])
//  - PE table: LN(patterns @ w2 + b2) as fp32 [512][1024]
// ---------------------------------------------------------------------------
__global__ void k0_pre(const float* __restrict__ patterns, const float* __restrict__ w2,
                       const float* __restrict__ b2, const float* __restrict__ ln2g,
                       const float* __restrict__ ln2b, const int* __restrict__ epoch,
                       const int* __restrict__ total_epochs,
                       float* __restrict__ invt, float* __restrict__ knT,
                       float* __restrict__ peb) {
  const int b = blockIdx.x, t = threadIdx.x;
  __shared__ float pat[64];
  __shared__ float red[8];

  if (b == 0 && t == 0) {
    float ep = (float)epoch[0], te = (float)total_epochs[0];
    float warm = te * 0.1f;
    float temp;
    if (ep < warm) temp = 2.0f;
    else {
      float prog = (ep - warm) / (te - warm);
      temp = fmaxf(0.7f, 2.0f - 1.3f * prog);
    }
    invt[0] = 1.0f / temp;
  }

  if (t < 64) pat[t] = patterns[b * 64 + t];
  __syncthreads();

  if (t < 64) {
    float v = pat[t];
    float s = v * v;
    #pragma unroll
    for (int m = 1; m < 64; m <<= 1) s += __shfl_xor(s, m);
    float scale = 1.0f / fmaxf(sqrtf(s), 1e-12f);
    knT[(size_t)t * 512 + b] = v * scale;
  }

  const int d0 = t * 4;
  float4 acc = *(const float4*)&b2[d0];
  #pragma unroll 8
  for (int k = 0; k < 64; ++k) {
    float pk = pat[k];
    float4 w = *(const float4*)&w2[(size_t)k * 1024 + d0];
    acc.x = fmaf(pk, w.x, acc.x);
    acc.y = fmaf(pk, w.y, acc.y);
    acc.z = fmaf(pk, w.z, acc.z);
    acc.w = fmaf(pk, w.w, acc.w);
  }
  float s1 = acc.x + acc.y + acc.z + acc.w;
  float s2 = acc.x*acc.x + acc.y*acc.y + acc.z*acc.z + acc.w*acc.w;
  #pragma unroll
  for (int m = 1; m < 64; m <<= 1) { s1 += __shfl_xor(s1, m); s2 += __shfl_xor(s2, m); }
  const int wid = t >> 6;
  if ((t & 63) == 0) { red[wid] = s1; red[wid + 4] = s2; }
  __syncthreads();
  s1 = red[0] + red[1] + red[2] + red[3];
  s2 = red[4] + red[5] + red[6] + red[7];
  float mu = s1 * (1.0f / 1024.0f);
  float var = s2 * (1.0f / 1024.0f) - mu * mu;
  float rstd = rsqrtf(var + 1e-5f);
  float4 g  = *(const float4*)&ln2g[d0];
  float4 bb = *(const float4*)&ln2b[d0];
  float4 o;
  o.x = (acc.x - mu) * rstd * g.x + bb.x;
  o.y = (acc.y - mu) * rstd * g.y + bb.y;
  o.z = (acc.z - mu) * rstd * g.z + bb.z;
  o.w = (acc.w - mu) * rstd * g.w + bb.w;
  *(float4*)&peb[(size_t)b * 1024 + d0] = o;
}

// ---------------------------------------------------------------------------
// K_FUSED: everything per 64-row block. 512 blocks x 256 threads.
// Phase A: GEMM1 with in-block K-split: 4 groups of 64 thr, each 8x8 tile
//          over 64 rows x 64 cols, K-range 256 per group.
// Phase R: cross-group LDS reduce + bias + LayerNorm + l2norm (group 0).
// Phase B: logits (Qn @ KnT) + argmax + Lg/Hi/As/PE writes (all threads).
// LDS union (floats):
//   A: xsT [0..8704)   = [g][32][68]   (g*2176 + k*68 + row)
//      w1s [8704..16896) = [g][32][64] (8704 + g*2048 + k*64 + c)
//   R: hacc [0..12288) = [g-1][64][64]   (reuse xsT/w1s space)
//      qns  [12288..16640) = [64][68]
//   B: kns [0..8448)   = [64][132]       (reuse)
//      qns stays; sidx [16640..16704)
// ---------------------------------------------------------------------------
__global__ __launch_bounds__(256) void k_fused(
    const float* __restrict__ x, const float* __restrict__ w1,
    const float* __restrict__ b1, const float* __restrict__ ln1g,
    const float* __restrict__ ln1b, const float* __restrict__ knT,
    const float* __restrict__ invtp, const float* __restrict__ peb,
    float* __restrict__ outPe, float* __restrict__ outAs,
    float* __restrict__ outLg, float* __restrict__ outHi,
    float* __restrict__ outQ) {
  __shared__ float smem[16896];
  const int tid = threadIdx.x;
  const int rowbase = blockIdx.x * 64;

  // ---------------- phase A: GEMM1, 4 K-groups ----------------
  const int g  = tid >> 6;          // K-group
  const int t  = tid & 63;
  const int rt = t >> 3, ct = t & 7;
  const int r0 = rt * 8, c0 = ct * 8;
  const int kbase = g * 256;

  float* xsT = smem;                // g*2176 + k*68 + row
  float* w1s = smem + 8704;         // g*2048 + k*64 + c

  float acc[8][8];
  #pragma unroll
  for (int i = 0; i < 8; ++i)
    #pragma unroll
    for (int j = 0; j < 8; ++j) acc[i][j] = 0.f;

  // per-thread staging bases
  const float* xp = x + (size_t)(rowbase + (t >> 3)) * 1024 + kbase + (t & 7) * 4;
  const int wkr = t >> 4;           // 0..3
  const int wc4 = (t & 15) * 4;

  for (int kt = 0; kt < 8; ++kt) {
    const int kb = kt * 32;
    float4 xv[8], wv[8];
    #pragma unroll
    for (int p = 0; p < 8; ++p)
      xv[p] = *(const float4*)(xp + (size_t)p * 8192 + kb);
    const float* wp = w1 + (size_t)(kbase + kb + wkr) * 64 + wc4;
    #pragma unroll
    for (int p = 0; p < 8; ++p)
      wv[p] = *(const float4*)(wp + (size_t)p * 256);
    __syncthreads();
    #pragma unroll
    for (int p = 0; p < 8; ++p) {
      const int row = (t >> 3) + 8 * p;
      const int kc4 = (t & 7) * 4;
      xsT[g*2176 + (kc4+0)*68 + row] = xv[p].x;
      xsT[g*2176 + (kc4+1)*68 + row] = xv[p].y;
      xsT[g*2176 + (kc4+2)*68 + row] = xv[p].z;
      xsT[g*2176 + (kc4+3)*68 + row] = xv[p].w;
    }
    #pragma unroll
    for (int p = 0; p < 8; ++p)
      *(float4*)&w1s[g*2048 + (wkr + 4*p)*64 + wc4] = wv[p];
    __syncthreads();
    #pragma unroll 4
    for (int kk = 0; kk < 32; ++kk) {
      float4 a0 = *(float4*)&xsT[g*2176 + kk*68 + r0];
      float4 a1 = *(float4*)&xsT[g*2176 + kk*68 + r0 + 4];
      float4 b0 = *(float4*)&w1s[g*2048 + kk*64 + c0];
      float4 b1v = *(float4*)&w1s[g*2048 + kk*64 + c0 + 4];
      float av[8] = {a0.x, a0.y, a0.z, a0.w, a1.x, a1.y, a1.z, a1.w};
      float bv[8] = {b0.x, b0.y, b0.z, b0.w, b1v.x, b1v.y, b1v.z, b1v.w};
      #pragma unroll
      for (int i = 0; i < 8; ++i)
        #pragma unroll
        for (int j = 0; j < 8; ++j)
          acc[i][j] = fmaf(av[i], bv[j], acc[i][j]);
    }
  }

  // ---------------- phase R: reduce + LN + l2norm ----------------
  __syncthreads();                  // all xsT/w1s reads done
  if (g > 0) {
    float* hc = smem + (g - 1) * 4096;
    #pragma unroll
    for (int i = 0; i < 8; ++i) {
      float4 v0, v1;
      v0.x = acc[i][0]; v0.y = acc[i][1]; v0.z = acc[i][2]; v0.w = acc[i][3];
      v1.x = acc[i][4]; v1.y = acc[i][5]; v1.z = acc[i][6]; v1.w = acc[i][7];
      *(float4*)&hc[(r0+i)*64 + c0]     = v0;
      *(float4*)&hc[(r0+i)*64 + c0 + 4] = v1;
    }
  }
  __syncthreads();
  float* qns = smem + 12288;        // [64][68]
  if (g == 0) {
    float bb[8], gg[8], ee[8];
    {
      float4 t0 = *(const float4*)&b1[c0];
      float4 t1 = *(const float4*)&b1[c0 + 4];
      float4 t2 = *(const float4*)&ln1g[c0];
      float4 t3 = *(const float4*)&ln1g[c0 + 4];
      float4 t4 = *(const float4*)&ln1b[c0];
      float4 t5 = *(const float4*)&ln1b[c0 + 4];
      bb[0]=t0.x; bb[1]=t0.y; bb[2]=t0.z; bb[3]=t0.w; bb[4]=t1.x; bb[5]=t1.y; bb[6]=t1.z; bb[7]=t1.w;
      gg[0]=t2.x; gg[1]=t2.y; gg[2]=t2.z; gg[3]=t2.w; gg[4]=t3.x; gg[5]=t3.y; gg[6]=t3.z; gg[7]=t3.w;
      ee[0]=t4.x; ee[1]=t4.y; ee[2]=t4.z; ee[3]=t4.w; ee[4]=t5.x; ee[5]=t5.y; ee[6]=t5.z; ee[7]=t5.w;
    }
    #pragma unroll
    for (int i = 0; i < 8; ++i) {
      const int row = r0 + i;
      float h[8];
      #pragma unroll
      for (int j = 0; j < 8; ++j) h[j] = acc[i][j] + bb[j];
      #pragma unroll
      for (int gg2 = 0; gg2 < 3; ++gg2) {
        float4 p0 = *(float4*)&smem[gg2*4096 + row*64 + c0];
        float4 p1 = *(float4*)&smem[gg2*4096 + row*64 + c0 + 4];
        h[0] += p0.x; h[1] += p0.y; h[2] += p0.z; h[3] += p0.w;
        h[4] += p1.x; h[5] += p1.y; h[6] += p1.z; h[7] += p1.w;
      }
      float s1 = 0.f, s2 = 0.f;
      #pragma unroll
      for (int j = 0; j < 8; ++j) { s1 += h[j]; s2 += h[j]*h[j]; }
      #pragma unroll
      for (int m = 1; m < 8; m <<= 1) { s1 += __shfl_xor(s1, m); s2 += __shfl_xor(s2, m); }
      const float mu   = s1 * 0.015625f;
      const float var  = s2 * 0.015625f - mu * mu;
      const float rstd = rsqrtf(var + 1e-5f);
      float q[8]; float t2s = 0.f;
      #pragma unroll
      for (int j = 0; j < 8; ++j) { q[j] = (h[j] - mu) * rstd * gg[j] + ee[j]; t2s += q[j]*q[j]; }
      #pragma unroll
      for (int m = 1; m < 8; m <<= 1) t2s += __shfl_xor(t2s, m);
      const float scl = 1.0f / fmaxf(sqrtf(t2s), 1e-12f);
      float4 qa, qc;
      qa.x = q[0]; qa.y = q[1]; qa.z = q[2]; qa.w = q[3];
      qc.x = q[4]; qc.y = q[5]; qc.z = q[6]; qc.w = q[7];
      *(float4*)&outQ[(size_t)(rowbase + row) * 64 + c0]     = qa;
      *(float4*)&outQ[(size_t)(rowbase + row) * 64 + c0 + 4] = qc;
      #pragma unroll
      for (int j = 0; j < 8; ++j) qns[row*68 + c0 + j] = q[j] * scl;
    }
  }

  // ---------------- phase B: logits + argmax ----------------
  const float invt = invtp[0];
  const int pt  = tid & 15;
  const int rt2 = tid >> 4;         // 0..15, rows rt2 + 16*i
  float* kns = smem;                // [64][132]
  int* sidx = (int*)(smem + 16640);

  float bm[4]; int bi[4];
  #pragma unroll
  for (int i = 0; i < 4; ++i) { bm[i] = -3.0e38f; bi[i] = 0; }

  for (int ch = 0; ch < 4; ++ch) {
    __syncthreads();                // qns visible / prior kns reads done / hacc dead
    #pragma unroll
    for (int p = 0; p < 8; ++p) {
      const int id = tid + p * 256;
      const int cr = id >> 5, pc = (id & 31) * 4;
      *(float4*)&kns[cr*132 + pc] = *(const float4*)&knT[(size_t)cr * 512 + ch * 128 + pc];
    }
    __syncthreads();

    float a2[4][8];
    #pragma unroll
    for (int i = 0; i < 4; ++i)
      #pragma unroll
      for (int j = 0; j < 8; ++j) a2[i][j] = 0.f;

    #pragma unroll 2
    for (int cb = 0; cb < 16; ++cb) {
      float qv[4][4];
      #pragma unroll
      for (int i = 0; i < 4; ++i) {
        float4 tq = *(float4*)&qns[(rt2 + 16*i)*68 + cb*4];
        qv[i][0] = tq.x; qv[i][1] = tq.y; qv[i][2] = tq.z; qv[i][3] = tq.w;
      }
      #pragma unroll
      for (int dc = 0; dc < 4; ++dc) {
        float4 k0 = *(float4*)&kns[(cb*4+dc)*132 + pt*8];
        float4 k1 = *(float4*)&kns[(cb*4+dc)*132 + pt*8 + 4];
        float kv[8] = {k0.x, k0.y, k0.z, k0.w, k1.x, k1.y, k1.z, k1.w};
        #pragma unroll
        for (int i = 0; i < 4; ++i)
          #pragma unroll
          for (int j = 0; j < 8; ++j)
            a2[i][j] = fmaf(qv[i][dc], kv[j], a2[i][j]);
      }
    }

    #pragma unroll
    for (int i = 0; i < 4; ++i) {
      const size_t row = (size_t)(rowbase + rt2 + 16*i);
      float v[8];
      #pragma unroll
      for (int j = 0; j < 8; ++j) v[j] = a2[i][j] * invt;
      const int pb = ch * 128 + pt * 8;
      #pragma unroll
      for (int j = 0; j < 8; ++j)
        if (v[j] > bm[i]) { bm[i] = v[j]; bi[i] = pb + j; }   // ascending, first max
      float4 o0, o1;
      o0.x = v[0]; o0.y = v[1]; o0.z = v[2]; o0.w = v[3];
      o1.x = v[4]; o1.y = v[5]; o1.z = v[6]; o1.w = v[7];
      *(float4*)&outLg[row * 512 + pb]     = o0;
      *(float4*)&outLg[row * 512 + pb + 4] = o1;
    }
  }

  // cross-thread argmax over pt (tie -> min index)
  #pragma unroll
  for (int i = 0; i < 4; ++i) {
    #pragma unroll
    for (int m = 1; m < 16; m <<= 1) {
      float ov = __shfl_xor(bm[i], m);
      int   oi = __shfl_xor(bi[i], m);
      if (ov > bm[i] || (ov == bm[i] && oi < bi[i])) { bm[i] = ov; bi[i] = oi; }
    }
    if (pt == 0) {
      sidx[rt2 + 16*i] = bi[i];
      outHi[rowbase + rt2 + 16*i] = (float)bi[i];
    }
  }
  __syncthreads();

  // ---------------- one-hot assignments ----------------
  #pragma unroll
  for (int p = 0; p < 32; ++p) {
    const int id = tid + p * 256;
    const int r = id >> 7, c4 = (id & 127) * 4;
    const int b = sidx[r];
    float4 z; z.x = 0.f; z.y = 0.f; z.z = 0.f; z.w = 0.f;
    if (b >= c4 && b < c4 + 4) ((float*)&z)[b - c4] = 1.0f;
    *(float4*)&outAs[(size_t)(rowbase + r) * 512 + c4] = z;
  }

  // ---------------- pattern_emb gather (PE table L2-hot) ----------------
  const float4* peb4 = (const float4*)peb;
  float4* o4 = (float4*)outPe;
  #pragma unroll 4
  for (int p = 0; p < 64; ++p) {
    const int id = tid + p * 256;
    const int r = id >> 8, c4 = id & 255;
    o4[(size_t)(rowbase + r) * 256 + c4] = peb4[(size_t)sidx[r] * 256 + c4];
  }
}

// ---------------------------------------------------------------------------
extern "C" void kernel_launch(void* const* d_in, const int* in_sizes, int n_in,
                              void* d_out, int out_size, void* d_ws, size_t ws_size,
                              hipStream_t stream) {
  (void)in_sizes; (void)n_in; (void)out_size; (void)ws_size;
  const float* x        = (const float*)d_in[0];
  const float* w1       = (const float*)d_in[1];
  const float* b1       = (const float*)d_in[2];
  const float* ln1g     = (const float*)d_in[3];
  const float* ln1b     = (const float*)d_in[4];
  const float* patterns = (const float*)d_in[5];
  const float* w2       = (const float*)d_in[6];
  const float* b2       = (const float*)d_in[7];
  const float* ln2g     = (const float*)d_in[8];
  const float* ln2b     = (const float*)d_in[9];
  const int*   epoch    = (const int*)d_in[10];
  const int*   total    = (const int*)d_in[11];

  float* out = (float*)d_out;
  float* outPe = out + O_PE;
  float* outAs = out + O_AS;
  float* outLg = out + O_LG;
  float* outHi = out + O_HI;
  float* outQ  = out + O_Q;

  // workspace (bytes): [0..256) invt | [256..131328) knT [64][512]
  //                    [131328..2228480) PE fp32 [512][1024]
  float* wsf  = (float*)d_ws;
  float* invt = wsf;
  float* knT  = wsf + 64;
  float* peb  = (float*)((char*)d_ws + 131328);

  hipLaunchKernelGGL(k0_pre, dim3(512), dim3(256), 0, stream,
                     patterns, w2, b2, ln2g, ln2b, epoch, total, invt, knT, peb);
  hipLaunchKernelGGL(k_fused, dim3(512), dim3(256), 0, stream,
                     x, w1, b1, ln1g, ln1b, knT, invt, peb,
                     outPe, outAs, outLg, outHi, outQ);
}